// Round 20
// baseline (278.430 us; speedup 1.0000x reference)
//
#include <hip/hip_runtime.h>

#define B_    64
#define N_    100
#define D_    32
#define F0    96
#define F1    160
#define F2    192
#define HID   256
#define FOUT  32

typedef unsigned short u16;
typedef unsigned int   u32;
typedef u16   u16x8 __attribute__((ext_vector_type(8)));
typedef u32   u32x2 __attribute__((ext_vector_type(2)));
typedef __bf16 bf16x8 __attribute__((ext_vector_type(8)));
typedef float  fx4   __attribute__((ext_vector_type(4)));

// hardware RNE f32->bf16
__device__ __forceinline__ u16 f2bf(float f) {
    return __builtin_bit_cast(u16, (__bf16)f);
}
// lrelu(v) = max(v, 0.2v): exact (v>0 -> v; v<=0 -> 0.2v)
__device__ __forceinline__ float lrelu(float v) { return fmaxf(v, 0.2f * v); }

__device__ __forceinline__ bf16x8 fragLds(const u16* p) {
    return __builtin_bit_cast(bf16x8, *(const u16x8*)p);
}
__device__ __forceinline__ bf16x8 fragGbl(const u16* __restrict__ p) {
    return __builtin_bit_cast(bf16x8, *(const u16x8*)p);
}
#define MFMA(a, b, c) __builtin_amdgcn_mfma_f32_16x16x32_bf16((a), (b), (c), 0, 0, 0)

// quad-gather: lanes q..q+3 hold bf16 for 4 consecutive u16 of one fragment
// row; quad-lead ((ld&3)==0, even) stores 8B; even-lane pk is valid.
__device__ __forceinline__ u32x2 quadPack(u32 h) {
    u32 h1 = (u32)__shfl_xor((int)h, 1, 64);
    u32 pk = h | (h1 << 16);
    u32 pko = (u32)__shfl_xor((int)pk, 2, 64);
    return (u32x2){pk, pko};
}

// ---- ws layout (bytes) ---- (P region unused; V kept at same offset)
#define OFF_P     0u
#define OFF_V     2457600u
#define OFF_AGG   4915200u
#define OFF_PACK  7372800u
#define PK_W1     0
#define PK_W2     15360
#define PK_N0     46080
#define PK_N1     103424
#define PK_N2     168960
#define PK_TOTAL  177152

#define PV_BLOCKS 1200         // V only: 6400*96 / 512 (P computed in edge)
#define PACK_BLOCKS 346

// ============================ prep ============================
__global__ __launch_bounds__(512) void prep_kernel(
    const float* __restrict__ x,
    const float* __restrict__ few0,
    const float* __restrict__ few1, const float* __restrict__ few2,
    const float* __restrict__ fnw0, const float* __restrict__ fnw1,
    const float* __restrict__ fnw2,
    float* __restrict__ V, u16* __restrict__ wpack)
{
    const int blk = blockIdx.x, tid = threadIdx.x;
    if (blk < PV_BLOCKS) {
        int o = blk * 512 + tid;           // < 6400*96
        int r = o / F0, k = o - r * F0;
        const float* xr = x + r * D_;
        float acc = 0.f;
        #pragma unroll
        for (int d = 0; d < D_; ++d) acc = fmaf(xr[d], few0[(D_ + d) * F0 + k], acc);
        V[r * F0 + k] = acc;
    } else {
        int p = (blk - PV_BLOCKS) * 512 + tid;
        const float* src; int start, Ncols, NT;
        if (p < PK_W2)      { start = PK_W1; src = few1; Ncols = F1;   NT = 10; }
        else if (p < PK_N0) { start = PK_W2; src = few2; Ncols = F2;   NT = 12; }
        else if (p < PK_N1) { start = PK_N0; src = fnw0; Ncols = HID;  NT = 16; }
        else if (p < PK_N2) { start = PK_N1; src = fnw1; Ncols = HID;  NT = 16; }
        else                { start = PK_N2; src = fnw2; Ncols = FOUT; NT = 2;  }
        int local = p - start;
        int j = local & 7, lane = (local >> 3) & 63, rest = local >> 9;
        int nt = rest % NT, kt = rest / NT;
        int n = 16 * nt + (lane & 15);
        int k = 32 * kt + 8 * (lane >> 4) + j;
        wpack[p] = f2bf(src[k * Ncols + n]);
    }
}

// ============================ edge ============================
// BARRIER-FREE SLICE OWNERSHIP: wave w (w<7) owns mt-slice w end-to-end.
// L1 computes all 10 nt for its slice -> sA1p slice w (disjoint per wave),
// then L2 immediately consumes its OWN slice for all 12 nt — the L1->L2
// __syncthreads() is ELIMINATED (same-wave LDS dependency only; LDS ops from
// one wave complete in order, compiler inserts lgkmcnt). Waves slip
// independently between the A0 barrier and the final agg barrier.
// Critical-wave MFMA 96 -> 90; wave 7 idles (latency-bound regime).
// All sA1p swizzle/quadPack formulas BYTE-IDENTICAL to the HW-verified ones
// (write (rowl*16)^((((rlo>>3)+2*lq)&7)<<4), read (ld*16)^(((ld>>3)&7)<<4),
// within each 1024B kt2-block; slice base mt*5120). Pad mask (mt<6)||(rlo==0)
// preserved. agg = deterministic 7-partial sum (f32, then one f2bf).
// PLATEAU LEDGER: occupancy pinned ~43% regardless of LDS (r5/7/8/12/13);
// (512,w>4) spills (~256/w arch budget); flat rebalance lost (r11); reg-A0
// lost (r12); sP removal lost (r14); load prefetch re-sunk by compiler (r17).
// Spill tripwire: WRITE_SIZE >> 2400 KB.
__global__ __launch_bounds__(512, 4) void edge_kernel(
    const float* __restrict__ x, const float* __restrict__ few0,
    const float* __restrict__ feb0, const float* __restrict__ V,
    const u16* __restrict__ W1p, const u16* __restrict__ W2p,
    const float* __restrict__ feb1, const float* __restrict__ feb2,
    u16* __restrict__ agg)
{
    const int i = blockIdx.x, b = blockIdx.y;
    const int tid = threadIdx.x, ld = tid & 63, wv = tid >> 6;
    const int row = b * N_ + i;

    __shared__ __align__(16) u16  sA0p[7 * 3 * 512];   // 21504 B
    __shared__ __align__(16) u16  sA1p[7 * 5 * 512];   // 35840 B (swizzled)
    __shared__ __align__(16) float sP[F0];             // 384 B
    __shared__ __align__(16) float sAggP[7 * F2];      // 5376 B [wave][f]

    // ---- compute P row in-block (bit-exact vs old prep: same FMA order) ----
    if (tid < F0) {
        const float* xr = x + (size_t)row * D_;
        float acc = feb0[tid];
        #pragma unroll
        for (int d = 0; d < D_; ++d) acc = fmaf(xr[d], few0[d * F0 + tid], acc);
        sP[tid] = acc;
    }
    __syncthreads();

    // ---- A0 packed build (vector, verified): pad rows -> 0 ----
    {
        const float* Vb = V + (size_t)b * N_ * F0;
        #pragma unroll
        for (int s = 0; s < 3; ++s) {
            int idx = tid + 512 * s;                   // < 1344 = 21*64
            if (idx < 1344) {
                int lane = idx & 63, rest = idx >> 6;  // rest < 21
                int kt = rest % 3, mt = rest / 3;
                int k = 32 * kt + 8 * (lane >> 4);
                int m = 16 * mt + (lane & 15);
                u16x8 w;
                if (m < N_) {
                    const float* vp = Vb + m * F0 + k;
                    fx4 v0 = *(const fx4*)(vp);
                    fx4 v1 = *(const fx4*)(vp + 4);
                    fx4 p0 = *(const fx4*)(sP + k);
                    fx4 p1 = *(const fx4*)(sP + k + 4);
                    #pragma unroll
                    for (int jj = 0; jj < 4; ++jj) {
                        w[jj]     = f2bf(lrelu(p0[jj] + v0[jj]));
                        w[4 + jj] = f2bf(lrelu(p1[jj] + v1[jj]));
                    }
                } else {
                    w = (u16x8){0, 0, 0, 0, 0, 0, 0, 0};
                }
                *(u16x8*)(sA0p + idx * 8) = w;
            }
        }
    }
    __syncthreads();

    const int c = ld & 15, rlo = (ld >> 4) * 4;
    const int a1off = (ld * 16) ^ (((ld >> 3) & 7) << 4);   // swz read offset

    if (wv < 7) {
        const int mt = wv;                 // owned slice

        // ---- L1 for own slice: all 10 nt (groups of 3 for acc ILP) ----
        bf16x8 a0[3];
        #pragma unroll
        for (int kt = 0; kt < 3; ++kt)
            a0[kt] = fragLds(sA0p + ((mt * 3 + kt) * 64 + ld) * 8);
        #pragma unroll
        for (int g = 0; g < 4; ++g) {
            const int cnt = (g < 3) ? 3 : 1;
            bf16x8 bw[3][3]; float bias[3];
            #pragma unroll
            for (int t = 0; t < 3; ++t) if (t < cnt) {
                int nt = 3 * g + t;
                bias[t] = feb1[16 * nt + c];
                #pragma unroll
                for (int kt = 0; kt < 3; ++kt)
                    bw[t][kt] = fragGbl(W1p + (size_t)((kt * 10 + nt) * 64 + ld) * 8);
            }
            fx4 acc[3];
            #pragma unroll
            for (int t = 0; t < 3; ++t) acc[t] = (fx4){0.f, 0.f, 0.f, 0.f};
            #pragma unroll
            for (int kt = 0; kt < 3; ++kt)
                #pragma unroll
                for (int t = 0; t < 3; ++t)
                    if (t < cnt) acc[t] = MFMA(a0[kt], bw[t][kt], acc[t]);
            // swizzled quad-packed repack into OWN slice (HW-verified formula)
            #pragma unroll
            for (int t = 0; t < 3; ++t) if (t < cnt) {
                int nt = 3 * g + t;
                int f = 16 * nt + c;
                int lq = (f >> 3) & 3;
                int S  = (((rlo >> 3) + 2 * lq) & 7) << 4;
                char* base = (char*)sA1p + (mt * 5 + (nt >> 1)) * 1024 + (c & 4) * 2;
                #pragma unroll
                for (int r = 0; r < 4; ++r) {
                    u32 h = (u32)f2bf(lrelu(acc[t][r] + bias[t]));
                    u32x2 two = quadPack(h);
                    int rowl = rlo + 16 * lq + r;
                    if ((ld & 3) == 0)
                        *(u32x2*)(base + ((rowl * 16) ^ S)) = two;
                }
            }
        }

        // ---- L2 for own slice: all 12 nt — NO block barrier needed ----
        bf16x8 a1[5];
        {
            const char* rb = (const char*)sA1p + mt * 5120 + a1off;
            #pragma unroll
            for (int kt = 0; kt < 5; ++kt)
                a1[kt] = fragLds((const u16*)(rb + kt * 1024));
        }
        #pragma unroll
        for (int g = 0; g < 4; ++g) {
            bf16x8 bw[3][5]; float bias[3];
            #pragma unroll
            for (int t = 0; t < 3; ++t) {
                int nt = 3 * g + t;
                bias[t] = feb2[16 * nt + c];
                #pragma unroll
                for (int kt = 0; kt < 5; ++kt)
                    bw[t][kt] = fragGbl(W2p + (size_t)((kt * 12 + nt) * 64 + ld) * 8);
            }
            fx4 acc[3];
            #pragma unroll
            for (int t = 0; t < 3; ++t) acc[t] = (fx4){0.f, 0.f, 0.f, 0.f};
            #pragma unroll
            for (int kt = 0; kt < 5; ++kt)
                #pragma unroll
                for (int t = 0; t < 3; ++t)
                    acc[t] = MFMA(a1[kt], bw[t][kt], acc[t]);
            // rows m = 16*mt + rlo + r ; mask pad rows (>=100); reduce; store
            float aggp[3];
            #pragma unroll
            for (int t = 0; t < 3; ++t) {
                float s = 0.f;
                if ((mt < 6) || (rlo == 0)) {
                    #pragma unroll
                    for (int r = 0; r < 4; ++r)
                        s += lrelu(acc[t][r] + bias[t]);
                }
                s += __shfl_xor(s, 16, 64);
                s += __shfl_xor(s, 32, 64);
                aggp[t] = s;
            }
            if (ld < 16) {
                #pragma unroll
                for (int t = 0; t < 3; ++t)
                    sAggP[wv * F2 + 16 * (3 * g + t) + ld] = aggp[t];
            }
        }
    }
    __syncthreads();

    if (tid < F2) {
        float v = sAggP[tid];
        #pragma unroll
        for (int w = 1; w < 7; ++w) v += sAggP[w * F2 + tid];
        agg[(size_t)row * F2 + tid] = f2bf(v);
    }
}

// ============================ node ============================
// EXACT r14/r15/r16 kernel (HW-verified: 400 blocks x 16 rows).
// 8 waves; waves own nt = wv and wv+8 (16 nt x 16 rows per layer).
// LDS 23.5KB. Layer-2 (N=32) on 2 waves. Same packed-weight layout as r10.
__global__ __launch_bounds__(512, 4) void node_kernel(
    const u16* __restrict__ agg, const float* __restrict__ x,
    const u16* __restrict__ n0p, const u16* __restrict__ n1p,
    const u16* __restrict__ n2p,
    const float* __restrict__ fnb0, const float* __restrict__ fnb1,
    const float* __restrict__ fnb2,
    float* __restrict__ out)
{
    const int blk = blockIdx.x;                 // 0..399, 16 rows each
    const int tid = threadIdx.x, ld = tid & 63, wv = tid >> 6;
    const int c = ld & 15, rlo = (ld >> 4) * 4;
    const int c0 = c & ~3;

    __shared__ __align__(16) u16 sH0p[7 * 512];   // 7168 B  [7kt][64][8]
    __shared__ __align__(16) u16 sH1p[8 * 512];   // 8192 B  [8kt2][64][8]
    __shared__ __align__(16) u16 sH2p[8 * 512];   // 8192 B

    // ---- stage H0 = [agg | x] packed-A for 16 rows (448 active threads) ----
    if (tid < 448) {
        int lane = tid & 63, kt = tid >> 6;       // kt < 7
        int k = 32 * kt + 8 * (lane >> 4);
        int m = lane & 15;
        int g = 16 * blk + m;
        u16x8 w;
        if (k < F2) {
            w = *(const u16x8*)(agg + (size_t)g * F2 + k);
        } else {
            const float* xp = x + (size_t)g * D_ + (k - F2);
            fx4 v0 = *(const fx4*)xp;
            fx4 v1 = *(const fx4*)(xp + 4);
            #pragma unroll
            for (int jj = 0; jj < 4; ++jj) {
                w[jj] = f2bf(v0[jj]); w[4 + jj] = f2bf(v1[jj]);
            }
        }
        *(u16x8*)(sH0p + tid * 8) = w;
    }
    __syncthreads();

    // ---- node layer 0: K=224 (7 kt), N=256 (nt = wv, wv+8), lrelu ----
    {
        fx4 acc[2];
        #pragma unroll
        for (int t = 0; t < 2; ++t) acc[t] = (fx4){0.f, 0.f, 0.f, 0.f};
        for (int kt = 0; kt < 7; ++kt) {
            bf16x8 a = fragLds(sH0p + (kt * 64 + ld) * 8);
            #pragma unroll
            for (int t = 0; t < 2; ++t) {
                int nt = wv + 8 * t;
                bf16x8 bw = fragGbl(n0p + (size_t)((kt * 16 + nt) * 64 + ld) * 8);
                acc[t] = MFMA(a, bw, acc[t]);
            }
        }
        #pragma unroll
        for (int t = 0; t < 2; ++t) {
            int f = 16 * (wv + 8 * t) + c;
            float bias = fnb0[f];
            int kt2 = f >> 5, lq = (f >> 3) & 3;
            u16* basep = sH1p + (kt2 * 64 + rlo + 16 * lq) * 8 + (c0 & 7);
            #pragma unroll
            for (int r = 0; r < 4; ++r) {
                u32 h = (u32)f2bf(lrelu(acc[t][r] + bias));
                u32x2 two = quadPack(h);
                if ((ld & 3) == 0)
                    *(u32x2*)(basep + r * 8) = two;
            }
        }
    }
    __syncthreads();

    // ---- node layer 1: K=256 (8 kt), N=256, lrelu ----
    {
        fx4 acc[2];
        #pragma unroll
        for (int t = 0; t < 2; ++t) acc[t] = (fx4){0.f, 0.f, 0.f, 0.f};
        for (int kt = 0; kt < 8; ++kt) {
            bf16x8 a = fragLds(sH1p + (kt * 64 + ld) * 8);
            #pragma unroll
            for (int t = 0; t < 2; ++t) {
                int nt = wv + 8 * t;
                bf16x8 bw = fragGbl(n1p + (size_t)((kt * 16 + nt) * 64 + ld) * 8);
                acc[t] = MFMA(a, bw, acc[t]);
            }
        }
        #pragma unroll
        for (int t = 0; t < 2; ++t) {
            int f = 16 * (wv + 8 * t) + c;
            float bias = fnb1[f];
            int kt2 = f >> 5, lq = (f >> 3) & 3;
            u16* basep = sH2p + (kt2 * 64 + rlo + 16 * lq) * 8 + (c0 & 7);
            #pragma unroll
            for (int r = 0; r < 4; ++r) {
                u32 h = (u32)f2bf(lrelu(acc[t][r] + bias));
                u32x2 two = quadPack(h);
                if ((ld & 3) == 0)
                    *(u32x2*)(basep + r * 8) = two;
            }
        }
    }
    __syncthreads();

    // ---- node layer 2: K=256 (8 kt), N=32 (2 nt), linear -> out ----
    if (wv < 2) {
        int nt = wv;
        fx4 acc = (fx4){0.f, 0.f, 0.f, 0.f};
        for (int kt = 0; kt < 8; ++kt) {
            bf16x8 a = fragLds(sH2p + (kt * 64 + ld) * 8);
            bf16x8 bw = fragGbl(n2p + (size_t)((kt * 2 + nt) * 64 + ld) * 8);
            acc = MFMA(a, bw, acc);
        }
        int f = 16 * nt + c;
        float bias = fnb2[f];
        #pragma unroll
        for (int r = 0; r < 4; ++r) {
            int g = 16 * blk + rlo + r;
            out[(size_t)g * FOUT + f] = acc[r] + bias;
        }
    }
}

extern "C" void kernel_launch(void* const* d_in, const int* in_sizes, int n_in,
                              void* d_out, int out_size, void* d_ws, size_t ws_size,
                              hipStream_t stream) {
    const float* x    = (const float*)d_in[0];
    const float* few0 = (const float*)d_in[1];
    const float* feb0 = (const float*)d_in[2];
    const float* few1 = (const float*)d_in[3];
    const float* feb1 = (const float*)d_in[4];
    const float* few2 = (const float*)d_in[5];
    const float* feb2 = (const float*)d_in[6];
    const float* fnw0 = (const float*)d_in[7];
    const float* fnb0 = (const float*)d_in[8];
    const float* fnw1 = (const float*)d_in[9];
    const float* fnb1 = (const float*)d_in[10];
    const float* fnw2 = (const float*)d_in[11];
    const float* fnb2 = (const float*)d_in[12];

    char* w = (char*)d_ws;
    float* V    = (float*)(w + OFF_V);
    u16*   aggb = (u16*)(w + OFF_AGG);
    u16*   pack = (u16*)(w + OFF_PACK);

    prep_kernel<<<PV_BLOCKS + PACK_BLOCKS, 512, 0, stream>>>(
        x, few0, few1, few2, fnw0, fnw1, fnw2, V, pack);

    edge_kernel<<<dim3(N_, B_), 512, 0, stream>>>(
        x, few0, feb0, V, pack + PK_W1, pack + PK_W2, feb1, feb2, aggb);

    node_kernel<<<400, 512, 0, stream>>>(
        aggb, x, pack + PK_N0, pack + PK_N1, pack + PK_N2,
        fnb0, fnb1, fnb2, (float*)d_out);
}

// Round 21
// 238.138 us; speedup vs baseline: 1.1692x; 1.1692x over previous
//
#include <hip/hip_runtime.h>

#define B_    64
#define N_    100
#define D_    32
#define F0    96
#define F1    160
#define F2    192
#define HID   256
#define FOUT  32

typedef unsigned short u16;
typedef unsigned int   u32;
typedef u16   u16x8 __attribute__((ext_vector_type(8)));
typedef u32   u32x2 __attribute__((ext_vector_type(2)));
typedef __bf16 bf16x8 __attribute__((ext_vector_type(8)));
typedef float  fx4   __attribute__((ext_vector_type(4)));

// hardware RNE f32->bf16
__device__ __forceinline__ u16 f2bf(float f) {
    return __builtin_bit_cast(u16, (__bf16)f);
}
// lrelu(v) = max(v, 0.2v): exact (v>0 -> v; v<=0 -> 0.2v)
__device__ __forceinline__ float lrelu(float v) { return fmaxf(v, 0.2f * v); }

__device__ __forceinline__ bf16x8 fragLds(const u16* p) {
    return __builtin_bit_cast(bf16x8, *(const u16x8*)p);
}
__device__ __forceinline__ bf16x8 fragGbl(const u16* __restrict__ p) {
    return __builtin_bit_cast(bf16x8, *(const u16x8*)p);
}
#define MFMA(a, b, c) __builtin_amdgcn_mfma_f32_16x16x32_bf16((a), (b), (c), 0, 0, 0)

// quad-gather: lanes q..q+3 hold bf16 for 4 consecutive u16 of one fragment
// row; quad-lead ((ld&3)==0, even) stores 8B; even-lane pk is valid.
__device__ __forceinline__ u32x2 quadPack(u32 h) {
    u32 h1 = (u32)__shfl_xor((int)h, 1, 64);
    u32 pk = h | (h1 << 16);
    u32 pko = (u32)__shfl_xor((int)pk, 2, 64);
    return (u32x2){pk, pko};
}

// ---- ws layout (bytes) ---- (P region unused; V kept at same offset)
#define OFF_P     0u
#define OFF_V     2457600u
#define OFF_AGG   4915200u
#define OFF_PACK  7372800u
#define PK_W1     0
#define PK_W2     15360
#define PK_N0     46080
#define PK_N1     103424
#define PK_N2     168960
#define PK_TOTAL  177152

#define PV_BLOCKS 1200         // V only: 6400*96 / 512 (P computed in edge)
#define PACK_BLOCKS 346

// ============================ prep ============================
__global__ __launch_bounds__(512) void prep_kernel(
    const float* __restrict__ x,
    const float* __restrict__ few0,
    const float* __restrict__ few1, const float* __restrict__ few2,
    const float* __restrict__ fnw0, const float* __restrict__ fnw1,
    const float* __restrict__ fnw2,
    float* __restrict__ V, u16* __restrict__ wpack)
{
    const int blk = blockIdx.x, tid = threadIdx.x;
    if (blk < PV_BLOCKS) {
        int o = blk * 512 + tid;           // < 6400*96
        int r = o / F0, k = o - r * F0;
        const float* xr = x + r * D_;
        float acc = 0.f;
        #pragma unroll
        for (int d = 0; d < D_; ++d) acc = fmaf(xr[d], few0[(D_ + d) * F0 + k], acc);
        V[r * F0 + k] = acc;
    } else {
        int p = (blk - PV_BLOCKS) * 512 + tid;
        const float* src; int start, Ncols, NT;
        if (p < PK_W2)      { start = PK_W1; src = few1; Ncols = F1;   NT = 10; }
        else if (p < PK_N0) { start = PK_W2; src = few2; Ncols = F2;   NT = 12; }
        else if (p < PK_N1) { start = PK_N0; src = fnw0; Ncols = HID;  NT = 16; }
        else if (p < PK_N2) { start = PK_N1; src = fnw1; Ncols = HID;  NT = 16; }
        else                { start = PK_N2; src = fnw2; Ncols = FOUT; NT = 2;  }
        int local = p - start;
        int j = local & 7, lane = (local >> 3) & 63, rest = local >> 9;
        int nt = rest % NT, kt = rest / NT;
        int n = 16 * nt + (lane & 15);
        int k = 32 * kt + 8 * (lane >> 4) + j;
        wpack[p] = f2bf(src[k * Ncols + n]);
    }
}

// ============================ edge ============================
// FINAL: EXACT r16 kernel — session-best verified (239.1us total; edge
// 165.4us, VGPR 52, zero spill, 0 bank conflicts, WRITE 2400KB).
// sP computed in-block (bit-exact FMA order vs old prep P).
// COMPLETE PLATEAU LEDGER (20 rounds):
//  - Occupancy PINNED ~43% regardless of LDS 59/44/38/35KB (r5/7/8/12/13):
//    unified VGPR+AGPR per-wave total caps waves/SIMD. Do not chase.
//  - launch_bounds (512,w) arch-VGPR budget ~= 256/w; w>4 spills (r5/r7/r8).
//  - L1 flat rebalance broke 3-chain acc ILP (r11, +15.5us).
//  - In-register A0 added critical-path VALU (r12, +37us).
//  - Split-J halves doubled weight/P traffic (r13, +33us).
//  - sP removal (r14, +4.7us); V-load prefetch re-sunk by compiler (r17).
//  - Barrier-free slice ownership 4x'd per-wave weight loads (r20, +49us):
//    the 8-wave barrier is CHEAPER than privatizing weights per wave.
//  - Swizzle (HW-verified, 0 conflicts): write (rowl*16)^((((rlo>>3)+2*lq)&7)<<4),
//    read (ld*16)^(((ld>>3)&7)<<4), within each 1024B kt2-block.
__global__ __launch_bounds__(512, 4) void edge_kernel(
    const float* __restrict__ x, const float* __restrict__ few0,
    const float* __restrict__ feb0, const float* __restrict__ V,
    const u16* __restrict__ W1p, const u16* __restrict__ W2p,
    const float* __restrict__ feb1, const float* __restrict__ feb2,
    u16* __restrict__ agg)
{
    const int i = blockIdx.x, b = blockIdx.y;
    const int tid = threadIdx.x, ld = tid & 63, wv = tid >> 6;
    const int wn = wv & 3, wm = wv >> 2;
    const int row = b * N_ + i;

    __shared__ __align__(16) u16  sA0p[7 * 3 * 512];   // 21504 B
    __shared__ __align__(16) u16  sA1p[7 * 5 * 512];   // 35840 B (swizzled)
    __shared__ __align__(16) float sP[F0];
    __shared__ __align__(16) float sAggP[2 * F2];      // [wm][f]

    // ---- compute P row in-block (bit-exact vs old prep: same FMA order) ----
    if (tid < F0) {
        const float* xr = x + (size_t)row * D_;
        float acc = feb0[tid];
        #pragma unroll
        for (int d = 0; d < D_; ++d) acc = fmaf(xr[d], few0[d * F0 + tid], acc);
        sP[tid] = acc;
    }
    __syncthreads();

    // ---- A0 packed build (vector, verified): pad rows -> 0 ----
    {
        const float* Vb = V + (size_t)b * N_ * F0;
        #pragma unroll
        for (int s = 0; s < 3; ++s) {
            int idx = tid + 512 * s;                   // < 1344 = 21*64
            if (idx < 1344) {
                int lane = idx & 63, rest = idx >> 6;  // rest < 21
                int kt = rest % 3, mt = rest / 3;
                int k = 32 * kt + 8 * (lane >> 4);
                int m = 16 * mt + (lane & 15);
                u16x8 w;
                if (m < N_) {
                    const float* vp = Vb + m * F0 + k;
                    fx4 v0 = *(const fx4*)(vp);
                    fx4 v1 = *(const fx4*)(vp + 4);
                    fx4 p0 = *(const fx4*)(sP + k);
                    fx4 p1 = *(const fx4*)(sP + k + 4);
                    #pragma unroll
                    for (int jj = 0; jj < 4; ++jj) {
                        w[jj]     = f2bf(lrelu(p0[jj] + v0[jj]));
                        w[4 + jj] = f2bf(lrelu(p1[jj] + v1[jj]));
                    }
                } else {
                    w = (u16x8){0, 0, 0, 0, 0, 0, 0, 0};
                }
                *(u16x8*)(sA0p + idx * 8) = w;
            }
        }
    }
    __syncthreads();

    const int mtB = wm ? 4 : 0, mtE = wm ? 7 : 4;
    const int c = ld & 15, rlo = (ld >> 4) * 4;
    const int a1off = (ld * 16) ^ (((ld >> 3) & 7) << 4);   // swz read offset

    // ---- edge layer 1: [112x96] @ [96x160] -> sA1p (swizzled packed-A) ----
    {
        const int nCnt = (wn < 2) ? 3 : 2;
        bf16x8 bw[3][3]; float bias[3];
        #pragma unroll
        for (int t = 0; t < 3; ++t) if (t < nCnt) {
            int nt = wn + 4 * t;
            bias[t] = feb1[16 * nt + c];
            #pragma unroll
            for (int kt = 0; kt < 3; ++kt)
                bw[t][kt] = fragGbl(W1p + (size_t)((kt * 10 + nt) * 64 + ld) * 8);
        }
        for (int mt = mtB; mt < mtE; ++mt) {
            bf16x8 a[3];
            #pragma unroll
            for (int kt = 0; kt < 3; ++kt)
                a[kt] = fragLds(sA0p + ((mt * 3 + kt) * 64 + ld) * 8);
            fx4 acc[3];
            #pragma unroll
            for (int t = 0; t < 3; ++t) acc[t] = (fx4){0.f, 0.f, 0.f, 0.f};
            #pragma unroll
            for (int kt = 0; kt < 3; ++kt)
                #pragma unroll
                for (int t = 0; t < 3; ++t)
                    if (t < nCnt) acc[t] = MFMA(a[kt], bw[t][kt], acc[t]);
            // swizzled quad-packed repack (HW-verified)
            #pragma unroll
            for (int t = 0; t < 3; ++t) if (t < nCnt) {
                int nt = wn + 4 * t;
                int f = 16 * nt + c;
                int lq = (f >> 3) & 3;
                int S  = (((rlo >> 3) + 2 * lq) & 7) << 4;
                char* base = (char*)sA1p + (mt * 5 + (nt >> 1)) * 1024 + (c & 4) * 2;
                #pragma unroll
                for (int r = 0; r < 4; ++r) {
                    u32 h = (u32)f2bf(lrelu(acc[t][r] + bias[t]));
                    u32x2 two = quadPack(h);
                    int rowl = rlo + 16 * lq + r;
                    if ((ld & 3) == 0)
                        *(u32x2*)(base + ((rowl * 16) ^ S)) = two;
                }
            }
        }
    }
    __syncthreads();

    // ---- edge layer 2 + fused aggregation over j (unchanged, verified) ----
    {
        bf16x8 bw[3][5]; float bias[3];
        float aggp[3] = {0.f, 0.f, 0.f};
        #pragma unroll
        for (int t = 0; t < 3; ++t) {
            int nt = wn + 4 * t;
            bias[t] = feb2[16 * nt + c];
            #pragma unroll
            for (int kt = 0; kt < 5; ++kt)
                bw[t][kt] = fragGbl(W2p + (size_t)((kt * 12 + nt) * 64 + ld) * 8);
        }
        for (int mt = mtB; mt < mtE; ++mt) {
            bf16x8 a[5];
            const char* rb = (const char*)sA1p + mt * 5120 + a1off;
            #pragma unroll
            for (int kt = 0; kt < 5; ++kt)
                a[kt] = fragLds((const u16*)(rb + kt * 1024));
            fx4 acc[3];
            #pragma unroll
            for (int t = 0; t < 3; ++t) acc[t] = (fx4){0.f, 0.f, 0.f, 0.f};
            #pragma unroll
            for (int kt = 0; kt < 5; ++kt)
                #pragma unroll
                for (int t = 0; t < 3; ++t)
                    acc[t] = MFMA(a[kt], bw[t][kt], acc[t]);
            // rows m = 16*mt + rlo + r ; mask out pad rows (>=100)
            bool ok = (mt < 6) || (rlo == 0);
            if (ok) {
                #pragma unroll
                for (int t = 0; t < 3; ++t)
                    #pragma unroll
                    for (int r = 0; r < 4; ++r)
                        aggp[t] += lrelu(acc[t][r] + bias[t]);
            }
        }
        #pragma unroll
        for (int t = 0; t < 3; ++t) {
            aggp[t] += __shfl_xor(aggp[t], 16, 64);
            aggp[t] += __shfl_xor(aggp[t], 32, 64);
        }
        if (ld < 16) {
            #pragma unroll
            for (int t = 0; t < 3; ++t)
                sAggP[wm * F2 + 16 * (wn + 4 * t) + ld] = aggp[t];
        }
    }
    __syncthreads();

    if (tid < F2) {
        float v = sAggP[tid] + sAggP[F2 + tid];
        agg[(size_t)row * F2 + tid] = f2bf(v);
    }
}

// ============================ node ============================
// EXACT r14/r15/r16 kernel (HW-verified: 400 blocks x 16 rows).
// 8 waves; waves own nt = wv and wv+8 (16 nt x 16 rows per layer).
// LDS 23.5KB. Layer-2 (N=32) on 2 waves. Same packed-weight layout as r10.
__global__ __launch_bounds__(512, 4) void node_kernel(
    const u16* __restrict__ agg, const float* __restrict__ x,
    const u16* __restrict__ n0p, const u16* __restrict__ n1p,
    const u16* __restrict__ n2p,
    const float* __restrict__ fnb0, const float* __restrict__ fnb1,
    const float* __restrict__ fnb2,
    float* __restrict__ out)
{
    const int blk = blockIdx.x;                 // 0..399, 16 rows each
    const int tid = threadIdx.x, ld = tid & 63, wv = tid >> 6;
    const int c = ld & 15, rlo = (ld >> 4) * 4;
    const int c0 = c & ~3;

    __shared__ __align__(16) u16 sH0p[7 * 512];   // 7168 B  [7kt][64][8]
    __shared__ __align__(16) u16 sH1p[8 * 512];   // 8192 B  [8kt2][64][8]
    __shared__ __align__(16) u16 sH2p[8 * 512];   // 8192 B

    // ---- stage H0 = [agg | x] packed-A for 16 rows (448 active threads) ----
    if (tid < 448) {
        int lane = tid & 63, kt = tid >> 6;       // kt < 7
        int k = 32 * kt + 8 * (lane >> 4);
        int m = lane & 15;
        int g = 16 * blk + m;
        u16x8 w;
        if (k < F2) {
            w = *(const u16x8*)(agg + (size_t)g * F2 + k);
        } else {
            const float* xp = x + (size_t)g * D_ + (k - F2);
            fx4 v0 = *(const fx4*)xp;
            fx4 v1 = *(const fx4*)(xp + 4);
            #pragma unroll
            for (int jj = 0; jj < 4; ++jj) {
                w[jj] = f2bf(v0[jj]); w[4 + jj] = f2bf(v1[jj]);
            }
        }
        *(u16x8*)(sH0p + tid * 8) = w;
    }
    __syncthreads();

    // ---- node layer 0: K=224 (7 kt), N=256 (nt = wv, wv+8), lrelu ----
    {
        fx4 acc[2];
        #pragma unroll
        for (int t = 0; t < 2; ++t) acc[t] = (fx4){0.f, 0.f, 0.f, 0.f};
        for (int kt = 0; kt < 7; ++kt) {
            bf16x8 a = fragLds(sH0p + (kt * 64 + ld) * 8);
            #pragma unroll
            for (int t = 0; t < 2; ++t) {
                int nt = wv + 8 * t;
                bf16x8 bw = fragGbl(n0p + (size_t)((kt * 16 + nt) * 64 + ld) * 8);
                acc[t] = MFMA(a, bw, acc[t]);
            }
        }
        #pragma unroll
        for (int t = 0; t < 2; ++t) {
            int f = 16 * (wv + 8 * t) + c;
            float bias = fnb0[f];
            int kt2 = f >> 5, lq = (f >> 3) & 3;
            u16* basep = sH1p + (kt2 * 64 + rlo + 16 * lq) * 8 + (c0 & 7);
            #pragma unroll
            for (int r = 0; r < 4; ++r) {
                u32 h = (u32)f2bf(lrelu(acc[t][r] + bias));
                u32x2 two = quadPack(h);
                if ((ld & 3) == 0)
                    *(u32x2*)(basep + r * 8) = two;
            }
        }
    }
    __syncthreads();

    // ---- node layer 1: K=256 (8 kt), N=256, lrelu ----
    {
        fx4 acc[2];
        #pragma unroll
        for (int t = 0; t < 2; ++t) acc[t] = (fx4){0.f, 0.f, 0.f, 0.f};
        for (int kt = 0; kt < 8; ++kt) {
            bf16x8 a = fragLds(sH1p + (kt * 64 + ld) * 8);
            #pragma unroll
            for (int t = 0; t < 2; ++t) {
                int nt = wv + 8 * t;
                bf16x8 bw = fragGbl(n1p + (size_t)((kt * 16 + nt) * 64 + ld) * 8);
                acc[t] = MFMA(a, bw, acc[t]);
            }
        }
        #pragma unroll
        for (int t = 0; t < 2; ++t) {
            int f = 16 * (wv + 8 * t) + c;
            float bias = fnb1[f];
            int kt2 = f >> 5, lq = (f >> 3) & 3;
            u16* basep = sH2p + (kt2 * 64 + rlo + 16 * lq) * 8 + (c0 & 7);
            #pragma unroll
            for (int r = 0; r < 4; ++r) {
                u32 h = (u32)f2bf(lrelu(acc[t][r] + bias));
                u32x2 two = quadPack(h);
                if ((ld & 3) == 0)
                    *(u32x2*)(basep + r * 8) = two;
            }
        }
    }
    __syncthreads();

    // ---- node layer 2: K=256 (8 kt), N=32 (2 nt), linear -> out ----
    if (wv < 2) {
        int nt = wv;
        fx4 acc = (fx4){0.f, 0.f, 0.f, 0.f};
        for (int kt = 0; kt < 8; ++kt) {
            bf16x8 a = fragLds(sH2p + (kt * 64 + ld) * 8);
            bf16x8 bw = fragGbl(n2p + (size_t)((kt * 2 + nt) * 64 + ld) * 8);
            acc = MFMA(a, bw, acc);
        }
        int f = 16 * nt + c;
        float bias = fnb2[f];
        #pragma unroll
        for (int r = 0; r < 4; ++r) {
            int g = 16 * blk + rlo + r;
            out[(size_t)g * FOUT + f] = acc[r] + bias;
        }
    }
}

extern "C" void kernel_launch(void* const* d_in, const int* in_sizes, int n_in,
                              void* d_out, int out_size, void* d_ws, size_t ws_size,
                              hipStream_t stream) {
    const float* x    = (const float*)d_in[0];
    const float* few0 = (const float*)d_in[1];
    const float* feb0 = (const float*)d_in[2];
    const float* few1 = (const float*)d_in[3];
    const float* feb1 = (const float*)d_in[4];
    const float* few2 = (const float*)d_in[5];
    const float* feb2 = (const float*)d_in[6];
    const float* fnw0 = (const float*)d_in[7];
    const float* fnb0 = (const float*)d_in[8];
    const float* fnw1 = (const float*)d_in[9];
    const float* fnb1 = (const float*)d_in[10];
    const float* fnw2 = (const float*)d_in[11];
    const float* fnb2 = (const float*)d_in[12];

    char* w = (char*)d_ws;
    float* V    = (float*)(w + OFF_V);
    u16*   aggb = (u16*)(w + OFF_AGG);
    u16*   pack = (u16*)(w + OFF_PACK);

    prep_kernel<<<PV_BLOCKS + PACK_BLOCKS, 512, 0, stream>>>(
        x, few0, few1, few2, fnw0, fnw1, fnw2, V, pack);

    edge_kernel<<<dim3(N_, B_), 512, 0, stream>>>(
        x, few0, feb0, V, pack + PK_W1, pack + PK_W2, feb1, feb2, aggb);

    node_kernel<<<400, 512, 0, stream>>>(
        aggb, x, pack + PK_N0, pack + PK_N1, pack + PK_N2,
        fnb0, fnb1, fnb2, (float*)d_out);
}

// Round 22
// 236.874 us; speedup vs baseline: 1.1754x; 1.0053x over previous
//
#include <hip/hip_runtime.h>

#define B_    64
#define N_    100
#define D_    32
#define F0    96
#define F1    160
#define F2    192
#define HID   256
#define FOUT  32

typedef unsigned short u16;
typedef unsigned int   u32;
typedef u16   u16x8 __attribute__((ext_vector_type(8)));
typedef u32   u32x2 __attribute__((ext_vector_type(2)));
typedef __bf16 bf16x8 __attribute__((ext_vector_type(8)));
typedef float  fx4   __attribute__((ext_vector_type(4)));

// hardware RNE f32->bf16
__device__ __forceinline__ u16 f2bf(float f) {
    return __builtin_bit_cast(u16, (__bf16)f);
}
// lrelu(v) = max(v, 0.2v): exact (v>0 -> v; v<=0 -> 0.2v)
__device__ __forceinline__ float lrelu(float v) { return fmaxf(v, 0.2f * v); }

__device__ __forceinline__ bf16x8 fragLds(const u16* p) {
    return __builtin_bit_cast(bf16x8, *(const u16x8*)p);
}
__device__ __forceinline__ bf16x8 fragGbl(const u16* __restrict__ p) {
    return __builtin_bit_cast(bf16x8, *(const u16x8*)p);
}
#define MFMA(a, b, c) __builtin_amdgcn_mfma_f32_16x16x32_bf16((a), (b), (c), 0, 0, 0)

// quad-gather: lanes q..q+3 hold bf16 for 4 consecutive u16 of one fragment
// row; quad-lead ((ld&3)==0, even) stores 8B; even-lane pk is valid.
__device__ __forceinline__ u32x2 quadPack(u32 h) {
    u32 h1 = (u32)__shfl_xor((int)h, 1, 64);
    u32 pk = h | (h1 << 16);
    u32 pko = (u32)__shfl_xor((int)pk, 2, 64);
    return (u32x2){pk, pko};
}

// ---- ws layout (bytes) ----
#define OFF_P     0u
#define OFF_V     2457600u
#define OFF_AGG   4915200u
#define OFF_PACK  7372800u
#define PK_W1     0
#define PK_W2     15360
#define PK_N0     46080
#define PK_N1     103424
#define PK_N2     168960
#define PK_TOTAL  177152

#define PV_BLOCKS 1200         // FUSED P+V: 6400*96 threads compute BOTH
#define PACK_BLOCKS 346

// ============================ prep ============================
// FUSED P+V (r21 lever): the V thread at (r,k) already loads x[r,:]; it now
// also computes P[r][k] (32 more FMA + L2-hot few0 upper half + 1 store) —
// NO extra blocks. r15<->r16 A/B showed: P-loaded edge = 160.7us (verified
// x3) vs P-in-edge 165.4, while P-as-separate-prep-blocks cost prep +10.5us.
// This fusion gets the fast edge without the prep-block cost.
// Bit-exact FMA orders preserved for both P and V (match original prep).
__global__ __launch_bounds__(512) void prep_kernel(
    const float* __restrict__ x,
    const float* __restrict__ few0, const float* __restrict__ feb0,
    const float* __restrict__ few1, const float* __restrict__ few2,
    const float* __restrict__ fnw0, const float* __restrict__ fnw1,
    const float* __restrict__ fnw2,
    float* __restrict__ P, float* __restrict__ V, u16* __restrict__ wpack)
{
    const int blk = blockIdx.x, tid = threadIdx.x;
    if (blk < PV_BLOCKS) {
        int o = blk * 512 + tid;           // < 6400*96
        int r = o / F0, k = o - r * F0;
        const float* xr = x + r * D_;
        float accV = 0.f;
        float accP = feb0[k];
        #pragma unroll
        for (int d = 0; d < D_; ++d) {
            float xv = xr[d];
            accV = fmaf(xv, few0[(D_ + d) * F0 + k], accV);
            accP = fmaf(xv, few0[d * F0 + k], accP);
        }
        V[r * F0 + k] = accV;
        P[r * F0 + k] = accP;
    } else {
        int p = (blk - PV_BLOCKS) * 512 + tid;
        const float* src; int start, Ncols, NT;
        if (p < PK_W2)      { start = PK_W1; src = few1; Ncols = F1;   NT = 10; }
        else if (p < PK_N0) { start = PK_W2; src = few2; Ncols = F2;   NT = 12; }
        else if (p < PK_N1) { start = PK_N0; src = fnw0; Ncols = HID;  NT = 16; }
        else if (p < PK_N2) { start = PK_N1; src = fnw1; Ncols = HID;  NT = 16; }
        else                { start = PK_N2; src = fnw2; Ncols = FOUT; NT = 2;  }
        int local = p - start;
        int j = local & 7, lane = (local >> 3) & 63, rest = local >> 9;
        int nt = rest % NT, kt = rest / NT;
        int n = 16 * nt + (lane & 15);
        int k = 32 * kt + 8 * (lane >> 4) + j;
        wpack[p] = f2bf(src[k * Ncols + n]);
    }
}

// ============================ edge ============================
// EXACT r10/r15 kernel (HW-verified x3 at 160.7-161.5us: VGPR 52, zero spill,
// swizzled sA1p, 0 bank conflicts, WRITE 2400KB). sP LOADED from P workspace.
// COMPLETE PLATEAU LEDGER (21 rounds):
//  - Occupancy PINNED ~43% regardless of LDS 59/44/38/35KB (r5/7/8/12/13).
//  - launch_bounds (512,w>4) spills (~256/w arch budget, r5/r7/r8).
//  - L1 flat rebalance broke 3-chain acc ILP (r11, +15.5us).
//  - In-register A0 (+37us, r12); split-J halves (+33us, r13).
//  - sP removal (+4.7us, r14); P-in-edge (+4.7us edge, r16);
//    V-load prefetch re-sunk by compiler (r17).
//  - Barrier-free slice ownership 4x'd per-wave weight loads (+49us, r20).
//  - Swizzle (HW-verified, 0 conflicts): write (rowl*16)^((((rlo>>3)+2*lq)&7)<<4),
//    read (ld*16)^(((ld>>3)&7)<<4), within each 1024B kt2-block.
__global__ __launch_bounds__(512, 4) void edge_kernel(
    const float* __restrict__ P, const float* __restrict__ V,
    const u16* __restrict__ W1p, const u16* __restrict__ W2p,
    const float* __restrict__ feb1, const float* __restrict__ feb2,
    u16* __restrict__ agg)
{
    const int i = blockIdx.x, b = blockIdx.y;
    const int tid = threadIdx.x, ld = tid & 63, wv = tid >> 6;
    const int wn = wv & 3, wm = wv >> 2;
    const int row = b * N_ + i;

    __shared__ __align__(16) u16  sA0p[7 * 3 * 512];   // 21504 B
    __shared__ __align__(16) u16  sA1p[7 * 5 * 512];   // 35840 B (swizzled)
    __shared__ __align__(16) float sP[F0];
    __shared__ __align__(16) float sAggP[2 * F2];      // [wm][f]

    if (tid < F0) sP[tid] = P[(size_t)row * F0 + tid];
    __syncthreads();

    // ---- A0 packed build (vector, verified): pad rows -> 0 ----
    {
        const float* Vb = V + (size_t)b * N_ * F0;
        #pragma unroll
        for (int s = 0; s < 3; ++s) {
            int idx = tid + 512 * s;                   // < 1344 = 21*64
            if (idx < 1344) {
                int lane = idx & 63, rest = idx >> 6;  // rest < 21
                int kt = rest % 3, mt = rest / 3;
                int k = 32 * kt + 8 * (lane >> 4);
                int m = 16 * mt + (lane & 15);
                u16x8 w;
                if (m < N_) {
                    const float* vp = Vb + m * F0 + k;
                    fx4 v0 = *(const fx4*)(vp);
                    fx4 v1 = *(const fx4*)(vp + 4);
                    fx4 p0 = *(const fx4*)(sP + k);
                    fx4 p1 = *(const fx4*)(sP + k + 4);
                    #pragma unroll
                    for (int jj = 0; jj < 4; ++jj) {
                        w[jj]     = f2bf(lrelu(p0[jj] + v0[jj]));
                        w[4 + jj] = f2bf(lrelu(p1[jj] + v1[jj]));
                    }
                } else {
                    w = (u16x8){0, 0, 0, 0, 0, 0, 0, 0};
                }
                *(u16x8*)(sA0p + idx * 8) = w;
            }
        }
    }
    __syncthreads();

    const int mtB = wm ? 4 : 0, mtE = wm ? 7 : 4;
    const int c = ld & 15, rlo = (ld >> 4) * 4;
    const int a1off = (ld * 16) ^ (((ld >> 3) & 7) << 4);   // swz read offset

    // ---- edge layer 1: [112x96] @ [96x160] -> sA1p (swizzled packed-A) ----
    {
        const int nCnt = (wn < 2) ? 3 : 2;
        bf16x8 bw[3][3]; float bias[3];
        #pragma unroll
        for (int t = 0; t < 3; ++t) if (t < nCnt) {
            int nt = wn + 4 * t;
            bias[t] = feb1[16 * nt + c];
            #pragma unroll
            for (int kt = 0; kt < 3; ++kt)
                bw[t][kt] = fragGbl(W1p + (size_t)((kt * 10 + nt) * 64 + ld) * 8);
        }
        for (int mt = mtB; mt < mtE; ++mt) {
            bf16x8 a[3];
            #pragma unroll
            for (int kt = 0; kt < 3; ++kt)
                a[kt] = fragLds(sA0p + ((mt * 3 + kt) * 64 + ld) * 8);
            fx4 acc[3];
            #pragma unroll
            for (int t = 0; t < 3; ++t) acc[t] = (fx4){0.f, 0.f, 0.f, 0.f};
            #pragma unroll
            for (int kt = 0; kt < 3; ++kt)
                #pragma unroll
                for (int t = 0; t < 3; ++t)
                    if (t < nCnt) acc[t] = MFMA(a[kt], bw[t][kt], acc[t]);
            // swizzled quad-packed repack (HW-verified)
            #pragma unroll
            for (int t = 0; t < 3; ++t) if (t < nCnt) {
                int nt = wn + 4 * t;
                int f = 16 * nt + c;
                int lq = (f >> 3) & 3;
                int S  = (((rlo >> 3) + 2 * lq) & 7) << 4;
                char* base = (char*)sA1p + (mt * 5 + (nt >> 1)) * 1024 + (c & 4) * 2;
                #pragma unroll
                for (int r = 0; r < 4; ++r) {
                    u32 h = (u32)f2bf(lrelu(acc[t][r] + bias[t]));
                    u32x2 two = quadPack(h);
                    int rowl = rlo + 16 * lq + r;
                    if ((ld & 3) == 0)
                        *(u32x2*)(base + ((rowl * 16) ^ S)) = two;
                }
            }
        }
    }
    __syncthreads();

    // ---- edge layer 2 + fused aggregation over j (unchanged, verified) ----
    {
        bf16x8 bw[3][5]; float bias[3];
        float aggp[3] = {0.f, 0.f, 0.f};
        #pragma unroll
        for (int t = 0; t < 3; ++t) {
            int nt = wn + 4 * t;
            bias[t] = feb2[16 * nt + c];
            #pragma unroll
            for (int kt = 0; kt < 5; ++kt)
                bw[t][kt] = fragGbl(W2p + (size_t)((kt * 12 + nt) * 64 + ld) * 8);
        }
        for (int mt = mtB; mt < mtE; ++mt) {
            bf16x8 a[5];
            const char* rb = (const char*)sA1p + mt * 5120 + a1off;
            #pragma unroll
            for (int kt = 0; kt < 5; ++kt)
                a[kt] = fragLds((const u16*)(rb + kt * 1024));
            fx4 acc[3];
            #pragma unroll
            for (int t = 0; t < 3; ++t) acc[t] = (fx4){0.f, 0.f, 0.f, 0.f};
            #pragma unroll
            for (int kt = 0; kt < 5; ++kt)
                #pragma unroll
                for (int t = 0; t < 3; ++t)
                    acc[t] = MFMA(a[kt], bw[t][kt], acc[t]);
            // rows m = 16*mt + rlo + r ; mask out pad rows (>=100)
            bool ok = (mt < 6) || (rlo == 0);
            if (ok) {
                #pragma unroll
                for (int t = 0; t < 3; ++t)
                    #pragma unroll
                    for (int r = 0; r < 4; ++r)
                        aggp[t] += lrelu(acc[t][r] + bias[t]);
            }
        }
        #pragma unroll
        for (int t = 0; t < 3; ++t) {
            aggp[t] += __shfl_xor(aggp[t], 16, 64);
            aggp[t] += __shfl_xor(aggp[t], 32, 64);
        }
        if (ld < 16) {
            #pragma unroll
            for (int t = 0; t < 3; ++t)
                sAggP[wm * F2 + 16 * (wn + 4 * t) + ld] = aggp[t];
        }
    }
    __syncthreads();

    if (tid < F2) {
        float v = sAggP[tid] + sAggP[F2 + tid];
        agg[(size_t)row * F2 + tid] = f2bf(v);
    }
}

// ============================ node ============================
// EXACT r14/r15/r16 kernel (HW-verified: 400 blocks x 16 rows).
// 8 waves; waves own nt = wv and wv+8 (16 nt x 16 rows per layer).
// LDS 23.5KB. Layer-2 (N=32) on 2 waves. Same packed-weight layout as r10.
__global__ __launch_bounds__(512, 4) void node_kernel(
    const u16* __restrict__ agg, const float* __restrict__ x,
    const u16* __restrict__ n0p, const u16* __restrict__ n1p,
    const u16* __restrict__ n2p,
    const float* __restrict__ fnb0, const float* __restrict__ fnb1,
    const float* __restrict__ fnb2,
    float* __restrict__ out)
{
    const int blk = blockIdx.x;                 // 0..399, 16 rows each
    const int tid = threadIdx.x, ld = tid & 63, wv = tid >> 6;
    const int c = ld & 15, rlo = (ld >> 4) * 4;
    const int c0 = c & ~3;

    __shared__ __align__(16) u16 sH0p[7 * 512];   // 7168 B  [7kt][64][8]
    __shared__ __align__(16) u16 sH1p[8 * 512];   // 8192 B  [8kt2][64][8]
    __shared__ __align__(16) u16 sH2p[8 * 512];   // 8192 B

    // ---- stage H0 = [agg | x] packed-A for 16 rows (448 active threads) ----
    if (tid < 448) {
        int lane = tid & 63, kt = tid >> 6;       // kt < 7
        int k = 32 * kt + 8 * (lane >> 4);
        int m = lane & 15;
        int g = 16 * blk + m;
        u16x8 w;
        if (k < F2) {
            w = *(const u16x8*)(agg + (size_t)g * F2 + k);
        } else {
            const float* xp = x + (size_t)g * D_ + (k - F2);
            fx4 v0 = *(const fx4*)xp;
            fx4 v1 = *(const fx4*)(xp + 4);
            #pragma unroll
            for (int jj = 0; jj < 4; ++jj) {
                w[jj] = f2bf(v0[jj]); w[4 + jj] = f2bf(v1[jj]);
            }
        }
        *(u16x8*)(sH0p + tid * 8) = w;
    }
    __syncthreads();

    // ---- node layer 0: K=224 (7 kt), N=256 (nt = wv, wv+8), lrelu ----
    {
        fx4 acc[2];
        #pragma unroll
        for (int t = 0; t < 2; ++t) acc[t] = (fx4){0.f, 0.f, 0.f, 0.f};
        for (int kt = 0; kt < 7; ++kt) {
            bf16x8 a = fragLds(sH0p + (kt * 64 + ld) * 8);
            #pragma unroll
            for (int t = 0; t < 2; ++t) {
                int nt = wv + 8 * t;
                bf16x8 bw = fragGbl(n0p + (size_t)((kt * 16 + nt) * 64 + ld) * 8);
                acc[t] = MFMA(a, bw, acc[t]);
            }
        }
        #pragma unroll
        for (int t = 0; t < 2; ++t) {
            int f = 16 * (wv + 8 * t) + c;
            float bias = fnb0[f];
            int kt2 = f >> 5, lq = (f >> 3) & 3;
            u16* basep = sH1p + (kt2 * 64 + rlo + 16 * lq) * 8 + (c0 & 7);
            #pragma unroll
            for (int r = 0; r < 4; ++r) {
                u32 h = (u32)f2bf(lrelu(acc[t][r] + bias));
                u32x2 two = quadPack(h);
                if ((ld & 3) == 0)
                    *(u32x2*)(basep + r * 8) = two;
            }
        }
    }
    __syncthreads();

    // ---- node layer 1: K=256 (8 kt), N=256, lrelu ----
    {
        fx4 acc[2];
        #pragma unroll
        for (int t = 0; t < 2; ++t) acc[t] = (fx4){0.f, 0.f, 0.f, 0.f};
        for (int kt = 0; kt < 8; ++kt) {
            bf16x8 a = fragLds(sH1p + (kt * 64 + ld) * 8);
            #pragma unroll
            for (int t = 0; t < 2; ++t) {
                int nt = wv + 8 * t;
                bf16x8 bw = fragGbl(n1p + (size_t)((kt * 16 + nt) * 64 + ld) * 8);
                acc[t] = MFMA(a, bw, acc[t]);
            }
        }
        #pragma unroll
        for (int t = 0; t < 2; ++t) {
            int f = 16 * (wv + 8 * t) + c;
            float bias = fnb1[f];
            int kt2 = f >> 5, lq = (f >> 3) & 3;
            u16* basep = sH2p + (kt2 * 64 + rlo + 16 * lq) * 8 + (c0 & 7);
            #pragma unroll
            for (int r = 0; r < 4; ++r) {
                u32 h = (u32)f2bf(lrelu(acc[t][r] + bias));
                u32x2 two = quadPack(h);
                if ((ld & 3) == 0)
                    *(u32x2*)(basep + r * 8) = two;
            }
        }
    }
    __syncthreads();

    // ---- node layer 2: K=256 (8 kt), N=32 (2 nt), linear -> out ----
    if (wv < 2) {
        int nt = wv;
        fx4 acc = (fx4){0.f, 0.f, 0.f, 0.f};
        for (int kt = 0; kt < 8; ++kt) {
            bf16x8 a = fragLds(sH2p + (kt * 64 + ld) * 8);
            bf16x8 bw = fragGbl(n2p + (size_t)((kt * 2 + nt) * 64 + ld) * 8);
            acc = MFMA(a, bw, acc);
        }
        int f = 16 * nt + c;
        float bias = fnb2[f];
        #pragma unroll
        for (int r = 0; r < 4; ++r) {
            int g = 16 * blk + rlo + r;
            out[(size_t)g * FOUT + f] = acc[r] + bias;
        }
    }
}

extern "C" void kernel_launch(void* const* d_in, const int* in_sizes, int n_in,
                              void* d_out, int out_size, void* d_ws, size_t ws_size,
                              hipStream_t stream) {
    const float* x    = (const float*)d_in[0];
    const float* few0 = (const float*)d_in[1];
    const float* feb0 = (const float*)d_in[2];
    const float* few1 = (const float*)d_in[3];
    const float* feb1 = (const float*)d_in[4];
    const float* few2 = (const float*)d_in[5];
    const float* feb2 = (const float*)d_in[6];
    const float* fnw0 = (const float*)d_in[7];
    const float* fnb0 = (const float*)d_in[8];
    const float* fnw1 = (const float*)d_in[9];
    const float* fnb1 = (const float*)d_in[10];
    const float* fnw2 = (const float*)d_in[11];
    const float* fnb2 = (const float*)d_in[12];

    char* w = (char*)d_ws;
    float* P    = (float*)(w + OFF_P);
    float* V    = (float*)(w + OFF_V);
    u16*   aggb = (u16*)(w + OFF_AGG);
    u16*   pack = (u16*)(w + OFF_PACK);

    prep_kernel<<<PV_BLOCKS + PACK_BLOCKS, 512, 0, stream>>>(
        x, few0, feb0, few1, few2, fnw0, fnw1, fnw2, P, V, pack);

    edge_kernel<<<dim3(N_, B_), 512, 0, stream>>>(
        P, V, pack + PK_W1, pack + PK_W2, feb1, feb2, aggb);

    node_kernel<<<400, 512, 0, stream>>>(
        aggb, x, pack + PK_N0, pack + PK_N1, pack + PK_N2,
        fnb0, fnb1, fnb2, (float*)d_out);
}

// Round 23
// 236.394 us; speedup vs baseline: 1.1778x; 1.0020x over previous
//
#include <hip/hip_runtime.h>

#define B_    64
#define N_    100
#define D_    32
#define F0    96
#define F1    160
#define F2    192
#define HID   256
#define FOUT  32

typedef unsigned short u16;
typedef unsigned int   u32;
typedef u16   u16x8 __attribute__((ext_vector_type(8)));
typedef u32   u32x2 __attribute__((ext_vector_type(2)));
typedef __bf16 bf16x8 __attribute__((ext_vector_type(8)));
typedef float  fx4   __attribute__((ext_vector_type(4)));

// hardware RNE f32->bf16
__device__ __forceinline__ u16 f2bf(float f) {
    return __builtin_bit_cast(u16, (__bf16)f);
}
// lrelu(v) = max(v, 0.2v): exact (v>0 -> v; v<=0 -> 0.2v)
__device__ __forceinline__ float lrelu(float v) { return fmaxf(v, 0.2f * v); }

__device__ __forceinline__ bf16x8 fragLds(const u16* p) {
    return __builtin_bit_cast(bf16x8, *(const u16x8*)p);
}
__device__ __forceinline__ bf16x8 fragGbl(const u16* __restrict__ p) {
    return __builtin_bit_cast(bf16x8, *(const u16x8*)p);
}
#define MFMA(a, b, c) __builtin_amdgcn_mfma_f32_16x16x32_bf16((a), (b), (c), 0, 0, 0)

// quad-gather: lanes q..q+3 hold bf16 for 4 consecutive u16 of one fragment
// row; quad-lead ((ld&3)==0, even) stores 8B; even-lane pk is valid.
__device__ __forceinline__ u32x2 quadPack(u32 h) {
    u32 h1 = (u32)__shfl_xor((int)h, 1, 64);
    u32 pk = h | (h1 << 16);
    u32 pko = (u32)__shfl_xor((int)pk, 2, 64);
    return (u32x2){pk, pko};
}

// ---- ws layout (bytes) ----
#define OFF_P     0u
#define OFF_V     2457600u
#define OFF_AGG   4915200u
#define OFF_PACK  7372800u
#define PK_W1     0
#define PK_W2     15360
#define PK_N0     46080
#define PK_N1     103424
#define PK_N2     168960
#define PK_TOTAL  177152

#define PV_BLOCKS 1200         // FUSED P+V: 6400*96 threads compute BOTH
#define PACK_BLOCKS 346

// ============================ prep ============================
// FUSED P+V (r22-verified): the V thread at (r,k) also computes P[r][k]
// (32 more FMA + L2-hot few0 upper half + 1 store) — NO extra blocks.
// Bit-exact FMA orders preserved for both P and V.
__global__ __launch_bounds__(512) void prep_kernel(
    const float* __restrict__ x,
    const float* __restrict__ few0, const float* __restrict__ feb0,
    const float* __restrict__ few1, const float* __restrict__ few2,
    const float* __restrict__ fnw0, const float* __restrict__ fnw1,
    const float* __restrict__ fnw2,
    float* __restrict__ P, float* __restrict__ V, u16* __restrict__ wpack)
{
    const int blk = blockIdx.x, tid = threadIdx.x;
    if (blk < PV_BLOCKS) {
        int o = blk * 512 + tid;           // < 6400*96
        int r = o / F0, k = o - r * F0;
        const float* xr = x + r * D_;
        float accV = 0.f;
        float accP = feb0[k];
        #pragma unroll
        for (int d = 0; d < D_; ++d) {
            float xv = xr[d];
            accV = fmaf(xv, few0[(D_ + d) * F0 + k], accV);
            accP = fmaf(xv, few0[d * F0 + k], accP);
        }
        V[r * F0 + k] = accV;
        P[r * F0 + k] = accP;
    } else {
        int p = (blk - PV_BLOCKS) * 512 + tid;
        const float* src; int start, Ncols, NT;
        if (p < PK_W2)      { start = PK_W1; src = few1; Ncols = F1;   NT = 10; }
        else if (p < PK_N0) { start = PK_W2; src = few2; Ncols = F2;   NT = 12; }
        else if (p < PK_N1) { start = PK_N0; src = fnw0; Ncols = HID;  NT = 16; }
        else if (p < PK_N2) { start = PK_N1; src = fnw1; Ncols = HID;  NT = 16; }
        else                { start = PK_N2; src = fnw2; Ncols = FOUT; NT = 2;  }
        int local = p - start;
        int j = local & 7, lane = (local >> 3) & 63, rest = local >> 9;
        int nt = rest % NT, kt = rest / NT;
        int n = 16 * nt + (lane & 15);
        int k = 32 * kt + 8 * (lane >> 4) + j;
        wpack[p] = f2bf(src[k * Ncols + n]);
    }
}

// ============================ edge ============================
// Base = r22 session-best (236.9us total; edge 161.8us, VGPR 52, zero spill,
// swizzled sA1p, 0 bank conflicts). sP LOADED from fused-prep P workspace.
// THIS ROUND (only change): mt loops rewritten with COMPILE-TIME trip count
// (s<4, wave-uniform guard mt<mtE) so the unroller can software-pipeline
// next-mt a[] LDS loads under the current MFMA chain (runtime trip bounds
// blocked unrolling before). Math/layout byte-identical.
// PLATEAU LEDGER: occupancy pinned ~43% (r5/7/8/12/13); (512,w>4) spills;
// flat rebalance lost (r11); reg-A0 lost (r12); split-J lost (r13); sP
// removal lost (r14); prefetch re-sunk (r17); barrier-free lost (r20).
// Swizzle (HW-verified, 0 conflicts): write (rowl*16)^((((rlo>>3)+2*lq)&7)<<4),
// read (ld*16)^(((ld>>3)&7)<<4), within each 1024B kt2-block.
// Spill tripwire: WRITE_SIZE >> 2400 KB.
__global__ __launch_bounds__(512, 4) void edge_kernel(
    const float* __restrict__ P, const float* __restrict__ V,
    const u16* __restrict__ W1p, const u16* __restrict__ W2p,
    const float* __restrict__ feb1, const float* __restrict__ feb2,
    u16* __restrict__ agg)
{
    const int i = blockIdx.x, b = blockIdx.y;
    const int tid = threadIdx.x, ld = tid & 63, wv = tid >> 6;
    const int wn = wv & 3, wm = wv >> 2;
    const int row = b * N_ + i;

    __shared__ __align__(16) u16  sA0p[7 * 3 * 512];   // 21504 B
    __shared__ __align__(16) u16  sA1p[7 * 5 * 512];   // 35840 B (swizzled)
    __shared__ __align__(16) float sP[F0];
    __shared__ __align__(16) float sAggP[2 * F2];      // [wm][f]

    if (tid < F0) sP[tid] = P[(size_t)row * F0 + tid];
    __syncthreads();

    // ---- A0 packed build (vector, verified): pad rows -> 0 ----
    {
        const float* Vb = V + (size_t)b * N_ * F0;
        #pragma unroll
        for (int s = 0; s < 3; ++s) {
            int idx = tid + 512 * s;                   // < 1344 = 21*64
            if (idx < 1344) {
                int lane = idx & 63, rest = idx >> 6;  // rest < 21
                int kt = rest % 3, mt = rest / 3;
                int k = 32 * kt + 8 * (lane >> 4);
                int m = 16 * mt + (lane & 15);
                u16x8 w;
                if (m < N_) {
                    const float* vp = Vb + m * F0 + k;
                    fx4 v0 = *(const fx4*)(vp);
                    fx4 v1 = *(const fx4*)(vp + 4);
                    fx4 p0 = *(const fx4*)(sP + k);
                    fx4 p1 = *(const fx4*)(sP + k + 4);
                    #pragma unroll
                    for (int jj = 0; jj < 4; ++jj) {
                        w[jj]     = f2bf(lrelu(p0[jj] + v0[jj]));
                        w[4 + jj] = f2bf(lrelu(p1[jj] + v1[jj]));
                    }
                } else {
                    w = (u16x8){0, 0, 0, 0, 0, 0, 0, 0};
                }
                *(u16x8*)(sA0p + idx * 8) = w;
            }
        }
    }
    __syncthreads();

    const int mtB = wm ? 4 : 0, mtE = wm ? 7 : 4;
    const int c = ld & 15, rlo = (ld >> 4) * 4;
    const int a1off = (ld * 16) ^ (((ld >> 3) & 7) << 4);   // swz read offset

    // ---- edge layer 1: [112x96] @ [96x160] -> sA1p (swizzled packed-A) ----
    {
        const int nCnt = (wn < 2) ? 3 : 2;
        bf16x8 bw[3][3]; float bias[3];
        #pragma unroll
        for (int t = 0; t < 3; ++t) if (t < nCnt) {
            int nt = wn + 4 * t;
            bias[t] = feb1[16 * nt + c];
            #pragma unroll
            for (int kt = 0; kt < 3; ++kt)
                bw[t][kt] = fragGbl(W1p + (size_t)((kt * 10 + nt) * 64 + ld) * 8);
        }
        #pragma unroll
        for (int s = 0; s < 4; ++s) {
            int mt = mtB + s;
            if (mt < mtE) {
                bf16x8 a[3];
                #pragma unroll
                for (int kt = 0; kt < 3; ++kt)
                    a[kt] = fragLds(sA0p + ((mt * 3 + kt) * 64 + ld) * 8);
                fx4 acc[3];
                #pragma unroll
                for (int t = 0; t < 3; ++t) acc[t] = (fx4){0.f, 0.f, 0.f, 0.f};
                #pragma unroll
                for (int kt = 0; kt < 3; ++kt)
                    #pragma unroll
                    for (int t = 0; t < 3; ++t)
                        if (t < nCnt) acc[t] = MFMA(a[kt], bw[t][kt], acc[t]);
                // swizzled quad-packed repack (HW-verified)
                #pragma unroll
                for (int t = 0; t < 3; ++t) if (t < nCnt) {
                    int nt = wn + 4 * t;
                    int f = 16 * nt + c;
                    int lq = (f >> 3) & 3;
                    int S  = (((rlo >> 3) + 2 * lq) & 7) << 4;
                    char* base = (char*)sA1p + (mt * 5 + (nt >> 1)) * 1024 + (c & 4) * 2;
                    #pragma unroll
                    for (int r = 0; r < 4; ++r) {
                        u32 h = (u32)f2bf(lrelu(acc[t][r] + bias[t]));
                        u32x2 two = quadPack(h);
                        int rowl = rlo + 16 * lq + r;
                        if ((ld & 3) == 0)
                            *(u32x2*)(base + ((rowl * 16) ^ S)) = two;
                    }
                }
            }
        }
    }
    __syncthreads();

    // ---- edge layer 2 + fused aggregation over j ----
    {
        bf16x8 bw[3][5]; float bias[3];
        float aggp[3] = {0.f, 0.f, 0.f};
        #pragma unroll
        for (int t = 0; t < 3; ++t) {
            int nt = wn + 4 * t;
            bias[t] = feb2[16 * nt + c];
            #pragma unroll
            for (int kt = 0; kt < 5; ++kt)
                bw[t][kt] = fragGbl(W2p + (size_t)((kt * 12 + nt) * 64 + ld) * 8);
        }
        #pragma unroll
        for (int s = 0; s < 4; ++s) {
            int mt = mtB + s;
            if (mt < mtE) {
                bf16x8 a[5];
                const char* rb = (const char*)sA1p + mt * 5120 + a1off;
                #pragma unroll
                for (int kt = 0; kt < 5; ++kt)
                    a[kt] = fragLds((const u16*)(rb + kt * 1024));
                fx4 acc[3];
                #pragma unroll
                for (int t = 0; t < 3; ++t) acc[t] = (fx4){0.f, 0.f, 0.f, 0.f};
                #pragma unroll
                for (int kt = 0; kt < 5; ++kt)
                    #pragma unroll
                    for (int t = 0; t < 3; ++t)
                        acc[t] = MFMA(a[kt], bw[t][kt], acc[t]);
                // rows m = 16*mt + rlo + r ; mask out pad rows (>=100)
                bool ok = (mt < 6) || (rlo == 0);
                if (ok) {
                    #pragma unroll
                    for (int t = 0; t < 3; ++t)
                        #pragma unroll
                        for (int r = 0; r < 4; ++r)
                            aggp[t] += lrelu(acc[t][r] + bias[t]);
                }
            }
        }
        #pragma unroll
        for (int t = 0; t < 3; ++t) {
            aggp[t] += __shfl_xor(aggp[t], 16, 64);
            aggp[t] += __shfl_xor(aggp[t], 32, 64);
        }
        if (ld < 16) {
            #pragma unroll
            for (int t = 0; t < 3; ++t)
                sAggP[wm * F2 + 16 * (wn + 4 * t) + ld] = aggp[t];
        }
    }
    __syncthreads();

    if (tid < F2) {
        float v = sAggP[tid] + sAggP[F2 + tid];
        agg[(size_t)row * F2 + tid] = f2bf(v);
    }
}

// ============================ node ============================
// EXACT r14/r15/r16/r22 kernel (HW-verified: 400 blocks x 16 rows).
__global__ __launch_bounds__(512, 4) void node_kernel(
    const u16* __restrict__ agg, const float* __restrict__ x,
    const u16* __restrict__ n0p, const u16* __restrict__ n1p,
    const u16* __restrict__ n2p,
    const float* __restrict__ fnb0, const float* __restrict__ fnb1,
    const float* __restrict__ fnb2,
    float* __restrict__ out)
{
    const int blk = blockIdx.x;                 // 0..399, 16 rows each
    const int tid = threadIdx.x, ld = tid & 63, wv = tid >> 6;
    const int c = ld & 15, rlo = (ld >> 4) * 4;
    const int c0 = c & ~3;

    __shared__ __align__(16) u16 sH0p[7 * 512];   // 7168 B  [7kt][64][8]
    __shared__ __align__(16) u16 sH1p[8 * 512];   // 8192 B  [8kt2][64][8]
    __shared__ __align__(16) u16 sH2p[8 * 512];   // 8192 B

    // ---- stage H0 = [agg | x] packed-A for 16 rows (448 active threads) ----
    if (tid < 448) {
        int lane = tid & 63, kt = tid >> 6;       // kt < 7
        int k = 32 * kt + 8 * (lane >> 4);
        int m = lane & 15;
        int g = 16 * blk + m;
        u16x8 w;
        if (k < F2) {
            w = *(const u16x8*)(agg + (size_t)g * F2 + k);
        } else {
            const float* xp = x + (size_t)g * D_ + (k - F2);
            fx4 v0 = *(const fx4*)xp;
            fx4 v1 = *(const fx4*)(xp + 4);
            #pragma unroll
            for (int jj = 0; jj < 4; ++jj) {
                w[jj] = f2bf(v0[jj]); w[4 + jj] = f2bf(v1[jj]);
            }
        }
        *(u16x8*)(sH0p + tid * 8) = w;
    }
    __syncthreads();

    // ---- node layer 0: K=224 (7 kt), N=256 (nt = wv, wv+8), lrelu ----
    {
        fx4 acc[2];
        #pragma unroll
        for (int t = 0; t < 2; ++t) acc[t] = (fx4){0.f, 0.f, 0.f, 0.f};
        for (int kt = 0; kt < 7; ++kt) {
            bf16x8 a = fragLds(sH0p + (kt * 64 + ld) * 8);
            #pragma unroll
            for (int t = 0; t < 2; ++t) {
                int nt = wv + 8 * t;
                bf16x8 bw = fragGbl(n0p + (size_t)((kt * 16 + nt) * 64 + ld) * 8);
                acc[t] = MFMA(a, bw, acc[t]);
            }
        }
        #pragma unroll
        for (int t = 0; t < 2; ++t) {
            int f = 16 * (wv + 8 * t) + c;
            float bias = fnb0[f];
            int kt2 = f >> 5, lq = (f >> 3) & 3;
            u16* basep = sH1p + (kt2 * 64 + rlo + 16 * lq) * 8 + (c0 & 7);
            #pragma unroll
            for (int r = 0; r < 4; ++r) {
                u32 h = (u32)f2bf(lrelu(acc[t][r] + bias));
                u32x2 two = quadPack(h);
                if ((ld & 3) == 0)
                    *(u32x2*)(basep + r * 8) = two;
            }
        }
    }
    __syncthreads();

    // ---- node layer 1: K=256 (8 kt), N=256, lrelu ----
    {
        fx4 acc[2];
        #pragma unroll
        for (int t = 0; t < 2; ++t) acc[t] = (fx4){0.f, 0.f, 0.f, 0.f};
        for (int kt = 0; kt < 8; ++kt) {
            bf16x8 a = fragLds(sH1p + (kt * 64 + ld) * 8);
            #pragma unroll
            for (int t = 0; t < 2; ++t) {
                int nt = wv + 8 * t;
                bf16x8 bw = fragGbl(n1p + (size_t)((kt * 16 + nt) * 64 + ld) * 8);
                acc[t] = MFMA(a, bw, acc[t]);
            }
        }
        #pragma unroll
        for (int t = 0; t < 2; ++t) {
            int f = 16 * (wv + 8 * t) + c;
            float bias = fnb1[f];
            int kt2 = f >> 5, lq = (f >> 3) & 3;
            u16* basep = sH2p + (kt2 * 64 + rlo + 16 * lq) * 8 + (c0 & 7);
            #pragma unroll
            for (int r = 0; r < 4; ++r) {
                u32 h = (u32)f2bf(lrelu(acc[t][r] + bias));
                u32x2 two = quadPack(h);
                if ((ld & 3) == 0)
                    *(u32x2*)(basep + r * 8) = two;
            }
        }
    }
    __syncthreads();

    // ---- node layer 2: K=256 (8 kt), N=32 (2 nt), linear -> out ----
    if (wv < 2) {
        int nt = wv;
        fx4 acc = (fx4){0.f, 0.f, 0.f, 0.f};
        for (int kt = 0; kt < 8; ++kt) {
            bf16x8 a = fragLds(sH2p + (kt * 64 + ld) * 8);
            bf16x8 bw = fragGbl(n2p + (size_t)((kt * 2 + nt) * 64 + ld) * 8);
            acc = MFMA(a, bw, acc);
        }
        int f = 16 * nt + c;
        float bias = fnb2[f];
        #pragma unroll
        for (int r = 0; r < 4; ++r) {
            int g = 16 * blk + rlo + r;
            out[(size_t)g * FOUT + f] = acc[r] + bias;
        }
    }
}

extern "C" void kernel_launch(void* const* d_in, const int* in_sizes, int n_in,
                              void* d_out, int out_size, void* d_ws, size_t ws_size,
                              hipStream_t stream) {
    const float* x    = (const float*)d_in[0];
    const float* few0 = (const float*)d_in[1];
    const float* feb0 = (const float*)d_in[2];
    const float* few1 = (const float*)d_in[3];
    const float* feb1 = (const float*)d_in[4];
    const float* few2 = (const float*)d_in[5];
    const float* feb2 = (const float*)d_in[6];
    const float* fnw0 = (const float*)d_in[7];
    const float* fnb0 = (const float*)d_in[8];
    const float* fnw1 = (const float*)d_in[9];
    const float* fnb1 = (const float*)d_in[10];
    const float* fnw2 = (const float*)d_in[11];
    const float* fnb2 = (const float*)d_in[12];

    char* w = (char*)d_ws;
    float* P    = (float*)(w + OFF_P);
    float* V    = (float*)(w + OFF_V);
    u16*   aggb = (u16*)(w + OFF_AGG);
    u16*   pack = (u16*)(w + OFF_PACK);

    prep_kernel<<<PV_BLOCKS + PACK_BLOCKS, 512, 0, stream>>>(
        x, few0, feb0, few1, few2, fnw0, fnw1, fnw2, P, V, pack);

    edge_kernel<<<dim3(N_, B_), 512, 0, stream>>>(
        P, V, pack + PK_W1, pack + PK_W2, feb1, feb2, aggb);

    node_kernel<<<400, 512, 0, stream>>>(
        aggb, x, pack + PK_N0, pack + PK_N1, pack + PK_N2,
        fnb0, fnb1, fnb2, (float*)d_out);
}

// Round 24
// 235.145 us; speedup vs baseline: 1.1841x; 1.0053x over previous
//
#include <hip/hip_runtime.h>

#define B_    64
#define N_    100
#define D_    32
#define F0    96
#define F1    160
#define F2    192
#define HID   256
#define FOUT  32

typedef unsigned short u16;
typedef unsigned int   u32;
typedef u16   u16x8 __attribute__((ext_vector_type(8)));
typedef u32   u32x2 __attribute__((ext_vector_type(2)));
typedef __bf16 bf16x8 __attribute__((ext_vector_type(8)));
typedef float  fx4   __attribute__((ext_vector_type(4)));

// hardware RNE f32->bf16
__device__ __forceinline__ u16 f2bf(float f) {
    return __builtin_bit_cast(u16, (__bf16)f);
}
// lrelu(v) = max(v, 0.2v): exact (v>0 -> v; v<=0 -> 0.2v)
__device__ __forceinline__ float lrelu(float v) { return fmaxf(v, 0.2f * v); }

__device__ __forceinline__ bf16x8 fragLds(const u16* p) {
    return __builtin_bit_cast(bf16x8, *(const u16x8*)p);
}
__device__ __forceinline__ bf16x8 fragGbl(const u16* __restrict__ p) {
    return __builtin_bit_cast(bf16x8, *(const u16x8*)p);
}
#define MFMA(a, b, c) __builtin_amdgcn_mfma_f32_16x16x32_bf16((a), (b), (c), 0, 0, 0)

// quad-gather: lanes q..q+3 hold bf16 for 4 consecutive u16 of one fragment
// row; quad-lead ((ld&3)==0, even) stores 8B; even-lane pk is valid.
__device__ __forceinline__ u32x2 quadPack(u32 h) {
    u32 h1 = (u32)__shfl_xor((int)h, 1, 64);
    u32 pk = h | (h1 << 16);
    u32 pko = (u32)__shfl_xor((int)pk, 2, 64);
    return (u32x2){pk, pko};
}

// ---- ws layout (bytes) ----
#define OFF_P     0u
#define OFF_V     2457600u
#define OFF_AGG   4915200u
#define OFF_PACK  7372800u
#define PK_W1     0
#define PK_W2     15360
#define PK_N0     46080
#define PK_N1     103424
#define PK_N2     168960
#define PK_TOTAL  177152

#define PV_BLOCKS 1200         // FUSED P+V: 6400*96 threads compute BOTH
#define PACK_BLOCKS 346

// ============================ prep ============================
// FUSED P+V (r22-verified): the V thread at (r,k) also computes P[r][k]
// (32 more FMA + L2-hot few0 upper half + 1 store) — NO extra blocks.
// Bit-exact FMA orders preserved for both P and V.
__global__ __launch_bounds__(512) void prep_kernel(
    const float* __restrict__ x,
    const float* __restrict__ few0, const float* __restrict__ feb0,
    const float* __restrict__ few1, const float* __restrict__ few2,
    const float* __restrict__ fnw0, const float* __restrict__ fnw1,
    const float* __restrict__ fnw2,
    float* __restrict__ P, float* __restrict__ V, u16* __restrict__ wpack)
{
    const int blk = blockIdx.x, tid = threadIdx.x;
    if (blk < PV_BLOCKS) {
        int o = blk * 512 + tid;           // < 6400*96
        int r = o / F0, k = o - r * F0;
        const float* xr = x + r * D_;
        float accV = 0.f;
        float accP = feb0[k];
        #pragma unroll
        for (int d = 0; d < D_; ++d) {
            float xv = xr[d];
            accV = fmaf(xv, few0[(D_ + d) * F0 + k], accV);
            accP = fmaf(xv, few0[d * F0 + k], accP);
        }
        V[r * F0 + k] = accV;
        P[r * F0 + k] = accP;
    } else {
        int p = (blk - PV_BLOCKS) * 512 + tid;
        const float* src; int start, Ncols, NT;
        if (p < PK_W2)      { start = PK_W1; src = few1; Ncols = F1;   NT = 10; }
        else if (p < PK_N0) { start = PK_W2; src = few2; Ncols = F2;   NT = 12; }
        else if (p < PK_N1) { start = PK_N0; src = fnw0; Ncols = HID;  NT = 16; }
        else if (p < PK_N2) { start = PK_N1; src = fnw1; Ncols = HID;  NT = 16; }
        else                { start = PK_N2; src = fnw2; Ncols = FOUT; NT = 2;  }
        int local = p - start;
        int j = local & 7, lane = (local >> 3) & 63, rest = local >> 9;
        int nt = rest % NT, kt = rest / NT;
        int n = 16 * nt + (lane & 15);
        int k = 32 * kt + 8 * (lane >> 4) + j;
        wpack[p] = f2bf(src[k * Ncols + n]);
    }
}

// ============================ edge ============================
// FINAL SESSION BEST (r23-verified: 236.4us total; edge 161.0-161.4us,
// VGPR 56, zero spill, 0 bank conflicts, WRITE 2400KB).
// sP LOADED from fused-prep P workspace; mt loops compile-time unrolled
// (s<4, wave-uniform guard) for cross-iteration ILP.
// This is a STRUCTURAL PLATEAU, not a HW roofline (MfmaUtil 18.6%):
//  - Occupancy PINNED ~43% regardless of LDS 59/44/38/35KB (r5/7/8/12/13):
//    unified VGPR+AGPR per-wave total caps waves/SIMD.
//  - launch_bounds (512,w>4) spills (~256/w arch budget, r5/r7/r8).
//  - L1 flat rebalance broke 3-chain acc ILP (r11, +15.5us).
//  - In-register A0 (+37us, r12); split-J halves (+33us, r13).
//  - sP removal (+4.7us, r14); P-in-edge (+4.7us edge, r16);
//    V-load prefetch re-sunk by compiler (r17).
//  - Barrier-free slice ownership 4x'd per-wave weight loads (+49us, r20):
//    the 8-wave barrier is CHEAPER than privatizing weights per wave.
//  - Swizzle (HW-verified, 0 conflicts): write (rowl*16)^((((rlo>>3)+2*lq)&7)<<4),
//    read (ld*16)^(((ld>>3)&7)<<4), within each 1024B kt2-block.
__global__ __launch_bounds__(512, 4) void edge_kernel(
    const float* __restrict__ P, const float* __restrict__ V,
    const u16* __restrict__ W1p, const u16* __restrict__ W2p,
    const float* __restrict__ feb1, const float* __restrict__ feb2,
    u16* __restrict__ agg)
{
    const int i = blockIdx.x, b = blockIdx.y;
    const int tid = threadIdx.x, ld = tid & 63, wv = tid >> 6;
    const int wn = wv & 3, wm = wv >> 2;
    const int row = b * N_ + i;

    __shared__ __align__(16) u16  sA0p[7 * 3 * 512];   // 21504 B
    __shared__ __align__(16) u16  sA1p[7 * 5 * 512];   // 35840 B (swizzled)
    __shared__ __align__(16) float sP[F0];
    __shared__ __align__(16) float sAggP[2 * F2];      // [wm][f]

    if (tid < F0) sP[tid] = P[(size_t)row * F0 + tid];
    __syncthreads();

    // ---- A0 packed build (vector, verified): pad rows -> 0 ----
    {
        const float* Vb = V + (size_t)b * N_ * F0;
        #pragma unroll
        for (int s = 0; s < 3; ++s) {
            int idx = tid + 512 * s;                   // < 1344 = 21*64
            if (idx < 1344) {
                int lane = idx & 63, rest = idx >> 6;  // rest < 21
                int kt = rest % 3, mt = rest / 3;
                int k = 32 * kt + 8 * (lane >> 4);
                int m = 16 * mt + (lane & 15);
                u16x8 w;
                if (m < N_) {
                    const float* vp = Vb + m * F0 + k;
                    fx4 v0 = *(const fx4*)(vp);
                    fx4 v1 = *(const fx4*)(vp + 4);
                    fx4 p0 = *(const fx4*)(sP + k);
                    fx4 p1 = *(const fx4*)(sP + k + 4);
                    #pragma unroll
                    for (int jj = 0; jj < 4; ++jj) {
                        w[jj]     = f2bf(lrelu(p0[jj] + v0[jj]));
                        w[4 + jj] = f2bf(lrelu(p1[jj] + v1[jj]));
                    }
                } else {
                    w = (u16x8){0, 0, 0, 0, 0, 0, 0, 0};
                }
                *(u16x8*)(sA0p + idx * 8) = w;
            }
        }
    }
    __syncthreads();

    const int mtB = wm ? 4 : 0, mtE = wm ? 7 : 4;
    const int c = ld & 15, rlo = (ld >> 4) * 4;
    const int a1off = (ld * 16) ^ (((ld >> 3) & 7) << 4);   // swz read offset

    // ---- edge layer 1: [112x96] @ [96x160] -> sA1p (swizzled packed-A) ----
    {
        const int nCnt = (wn < 2) ? 3 : 2;
        bf16x8 bw[3][3]; float bias[3];
        #pragma unroll
        for (int t = 0; t < 3; ++t) if (t < nCnt) {
            int nt = wn + 4 * t;
            bias[t] = feb1[16 * nt + c];
            #pragma unroll
            for (int kt = 0; kt < 3; ++kt)
                bw[t][kt] = fragGbl(W1p + (size_t)((kt * 10 + nt) * 64 + ld) * 8);
        }
        #pragma unroll
        for (int s = 0; s < 4; ++s) {
            int mt = mtB + s;
            if (mt < mtE) {
                bf16x8 a[3];
                #pragma unroll
                for (int kt = 0; kt < 3; ++kt)
                    a[kt] = fragLds(sA0p + ((mt * 3 + kt) * 64 + ld) * 8);
                fx4 acc[3];
                #pragma unroll
                for (int t = 0; t < 3; ++t) acc[t] = (fx4){0.f, 0.f, 0.f, 0.f};
                #pragma unroll
                for (int kt = 0; kt < 3; ++kt)
                    #pragma unroll
                    for (int t = 0; t < 3; ++t)
                        if (t < nCnt) acc[t] = MFMA(a[kt], bw[t][kt], acc[t]);
                // swizzled quad-packed repack (HW-verified)
                #pragma unroll
                for (int t = 0; t < 3; ++t) if (t < nCnt) {
                    int nt = wn + 4 * t;
                    int f = 16 * nt + c;
                    int lq = (f >> 3) & 3;
                    int S  = (((rlo >> 3) + 2 * lq) & 7) << 4;
                    char* base = (char*)sA1p + (mt * 5 + (nt >> 1)) * 1024 + (c & 4) * 2;
                    #pragma unroll
                    for (int r = 0; r < 4; ++r) {
                        u32 h = (u32)f2bf(lrelu(acc[t][r] + bias[t]));
                        u32x2 two = quadPack(h);
                        int rowl = rlo + 16 * lq + r;
                        if ((ld & 3) == 0)
                            *(u32x2*)(base + ((rowl * 16) ^ S)) = two;
                    }
                }
            }
        }
    }
    __syncthreads();

    // ---- edge layer 2 + fused aggregation over j ----
    {
        bf16x8 bw[3][5]; float bias[3];
        float aggp[3] = {0.f, 0.f, 0.f};
        #pragma unroll
        for (int t = 0; t < 3; ++t) {
            int nt = wn + 4 * t;
            bias[t] = feb2[16 * nt + c];
            #pragma unroll
            for (int kt = 0; kt < 5; ++kt)
                bw[t][kt] = fragGbl(W2p + (size_t)((kt * 12 + nt) * 64 + ld) * 8);
        }
        #pragma unroll
        for (int s = 0; s < 4; ++s) {
            int mt = mtB + s;
            if (mt < mtE) {
                bf16x8 a[5];
                const char* rb = (const char*)sA1p + mt * 5120 + a1off;
                #pragma unroll
                for (int kt = 0; kt < 5; ++kt)
                    a[kt] = fragLds((const u16*)(rb + kt * 1024));
                fx4 acc[3];
                #pragma unroll
                for (int t = 0; t < 3; ++t) acc[t] = (fx4){0.f, 0.f, 0.f, 0.f};
                #pragma unroll
                for (int kt = 0; kt < 5; ++kt)
                    #pragma unroll
                    for (int t = 0; t < 3; ++t)
                        acc[t] = MFMA(a[kt], bw[t][kt], acc[t]);
                // rows m = 16*mt + rlo + r ; mask out pad rows (>=100)
                bool ok = (mt < 6) || (rlo == 0);
                if (ok) {
                    #pragma unroll
                    for (int t = 0; t < 3; ++t)
                        #pragma unroll
                        for (int r = 0; r < 4; ++r)
                            aggp[t] += lrelu(acc[t][r] + bias[t]);
                }
            }
        }
        #pragma unroll
        for (int t = 0; t < 3; ++t) {
            aggp[t] += __shfl_xor(aggp[t], 16, 64);
            aggp[t] += __shfl_xor(aggp[t], 32, 64);
        }
        if (ld < 16) {
            #pragma unroll
            for (int t = 0; t < 3; ++t)
                sAggP[wm * F2 + 16 * (wn + 4 * t) + ld] = aggp[t];
        }
    }
    __syncthreads();

    if (tid < F2) {
        float v = sAggP[tid] + sAggP[F2 + tid];
        agg[(size_t)row * F2 + tid] = f2bf(v);
    }
}

// ============================ node ============================
// EXACT r14/r15/r16/r22/r23 kernel (HW-verified: 400 blocks x 16 rows).
__global__ __launch_bounds__(512, 4) void node_kernel(
    const u16* __restrict__ agg, const float* __restrict__ x,
    const u16* __restrict__ n0p, const u16* __restrict__ n1p,
    const u16* __restrict__ n2p,
    const float* __restrict__ fnb0, const float* __restrict__ fnb1,
    const float* __restrict__ fnb2,
    float* __restrict__ out)
{
    const int blk = blockIdx.x;                 // 0..399, 16 rows each
    const int tid = threadIdx.x, ld = tid & 63, wv = tid >> 6;
    const int c = ld & 15, rlo = (ld >> 4) * 4;
    const int c0 = c & ~3;

    __shared__ __align__(16) u16 sH0p[7 * 512];   // 7168 B  [7kt][64][8]
    __shared__ __align__(16) u16 sH1p[8 * 512];   // 8192 B  [8kt2][64][8]
    __shared__ __align__(16) u16 sH2p[8 * 512];   // 8192 B

    // ---- stage H0 = [agg | x] packed-A for 16 rows (448 active threads) ----
    if (tid < 448) {
        int lane = tid & 63, kt = tid >> 6;       // kt < 7
        int k = 32 * kt + 8 * (lane >> 4);
        int m = lane & 15;
        int g = 16 * blk + m;
        u16x8 w;
        if (k < F2) {
            w = *(const u16x8*)(agg + (size_t)g * F2 + k);
        } else {
            const float* xp = x + (size_t)g * D_ + (k - F2);
            fx4 v0 = *(const fx4*)xp;
            fx4 v1 = *(const fx4*)(xp + 4);
            #pragma unroll
            for (int jj = 0; jj < 4; ++jj) {
                w[jj] = f2bf(v0[jj]); w[4 + jj] = f2bf(v1[jj]);
            }
        }
        *(u16x8*)(sH0p + tid * 8) = w;
    }
    __syncthreads();

    // ---- node layer 0: K=224 (7 kt), N=256 (nt = wv, wv+8), lrelu ----
    {
        fx4 acc[2];
        #pragma unroll
        for (int t = 0; t < 2; ++t) acc[t] = (fx4){0.f, 0.f, 0.f, 0.f};
        for (int kt = 0; kt < 7; ++kt) {
            bf16x8 a = fragLds(sH0p + (kt * 64 + ld) * 8);
            #pragma unroll
            for (int t = 0; t < 2; ++t) {
                int nt = wv + 8 * t;
                bf16x8 bw = fragGbl(n0p + (size_t)((kt * 16 + nt) * 64 + ld) * 8);
                acc[t] = MFMA(a, bw, acc[t]);
            }
        }
        #pragma unroll
        for (int t = 0; t < 2; ++t) {
            int f = 16 * (wv + 8 * t) + c;
            float bias = fnb0[f];
            int kt2 = f >> 5, lq = (f >> 3) & 3;
            u16* basep = sH1p + (kt2 * 64 + rlo + 16 * lq) * 8 + (c0 & 7);
            #pragma unroll
            for (int r = 0; r < 4; ++r) {
                u32 h = (u32)f2bf(lrelu(acc[t][r] + bias));
                u32x2 two = quadPack(h);
                if ((ld & 3) == 0)
                    *(u32x2*)(basep + r * 8) = two;
            }
        }
    }
    __syncthreads();

    // ---- node layer 1: K=256 (8 kt), N=256, lrelu ----
    {
        fx4 acc[2];
        #pragma unroll
        for (int t = 0; t < 2; ++t) acc[t] = (fx4){0.f, 0.f, 0.f, 0.f};
        for (int kt = 0; kt < 8; ++kt) {
            bf16x8 a = fragLds(sH1p + (kt * 64 + ld) * 8);
            #pragma unroll
            for (int t = 0; t < 2; ++t) {
                int nt = wv + 8 * t;
                bf16x8 bw = fragGbl(n1p + (size_t)((kt * 16 + nt) * 64 + ld) * 8);
                acc[t] = MFMA(a, bw, acc[t]);
            }
        }
        #pragma unroll
        for (int t = 0; t < 2; ++t) {
            int f = 16 * (wv + 8 * t) + c;
            float bias = fnb1[f];
            int kt2 = f >> 5, lq = (f >> 3) & 3;
            u16* basep = sH2p + (kt2 * 64 + rlo + 16 * lq) * 8 + (c0 & 7);
            #pragma unroll
            for (int r = 0; r < 4; ++r) {
                u32 h = (u32)f2bf(lrelu(acc[t][r] + bias));
                u32x2 two = quadPack(h);
                if ((ld & 3) == 0)
                    *(u32x2*)(basep + r * 8) = two;
            }
        }
    }
    __syncthreads();

    // ---- node layer 2: K=256 (8 kt), N=32 (2 nt), linear -> out ----
    if (wv < 2) {
        int nt = wv;
        fx4 acc = (fx4){0.f, 0.f, 0.f, 0.f};
        for (int kt = 0; kt < 8; ++kt) {
            bf16x8 a = fragLds(sH2p + (kt * 64 + ld) * 8);
            bf16x8 bw = fragGbl(n2p + (size_t)((kt * 2 + nt) * 64 + ld) * 8);
            acc = MFMA(a, bw, acc);
        }
        int f = 16 * nt + c;
        float bias = fnb2[f];
        #pragma unroll
        for (int r = 0; r < 4; ++r) {
            int g = 16 * blk + rlo + r;
            out[(size_t)g * FOUT + f] = acc[r] + bias;
        }
    }
}

extern "C" void kernel_launch(void* const* d_in, const int* in_sizes, int n_in,
                              void* d_out, int out_size, void* d_ws, size_t ws_size,
                              hipStream_t stream) {
    const float* x    = (const float*)d_in[0];
    const float* few0 = (const float*)d_in[1];
    const float* feb0 = (const float*)d_in[2];
    const float* few1 = (const float*)d_in[3];
    const float* feb1 = (const float*)d_in[4];
    const float* few2 = (const float*)d_in[5];
    const float* feb2 = (const float*)d_in[6];
    const float* fnw0 = (const float*)d_in[7];
    const float* fnb0 = (const float*)d_in[8];
    const float* fnw1 = (const float*)d_in[9];
    const float* fnb1 = (const float*)d_in[10];
    const float* fnw2 = (const float*)d_in[11];
    const float* fnb2 = (const float*)d_in[12];

    char* w = (char*)d_ws;
    float* P    = (float*)(w + OFF_P);
    float* V    = (float*)(w + OFF_V);
    u16*   aggb = (u16*)(w + OFF_AGG);
    u16*   pack = (u16*)(w + OFF_PACK);

    prep_kernel<<<PV_BLOCKS + PACK_BLOCKS, 512, 0, stream>>>(
        x, few0, feb0, few1, few2, fnw0, fnw1, fnw2, P, V, pack);

    edge_kernel<<<dim3(N_, B_), 512, 0, stream>>>(
        P, V, pack + PK_W1, pack + PK_W2, feb1, feb2, aggb);

    node_kernel<<<400, 512, 0, stream>>>(
        aggb, x, pack + PK_N0, pack + PK_N1, pack + PK_N2,
        fnb0, fnb1, fnb2, (float*)d_out);
}